// Round 9
// baseline (45.304 us; speedup 1.0000x reference)
//
#include <hip/hip_runtime.h>

#pragma clang fp contract(off)

typedef unsigned long long u64;

#define TOPK 5
#define WAVES 4

// branchless compare-exchange on u64 keys (ascending)
#define CE(x, y) do { const u64 _a = (x), _b = (y); const bool _l = _b < _a; \
                      (x) = _l ? _b : _a; (y) = _l ? _a : _b; } while (0)

// branchless sorted-insert of nk into ascending 5-list
#define INSERT(nk, k0, k1, k2, k3, k4) do {        \
    const u64 _n = (nk);                           \
    const bool l0 = _n < k0;                       \
    const bool l1 = _n < k1;                       \
    const bool l2 = _n < k2;                       \
    const bool l3 = _n < k3;                       \
    const bool l4 = _n < k4;                       \
    k4 = l4 ? (l3 ? k3 : _n) : k4;                 \
    k3 = l3 ? (l2 ? k2 : _n) : k3;                 \
    k2 = l2 ? (l1 ? k1 : _n) : k2;                 \
    k1 = l1 ? (l0 ? k0 : _n) : k1;                 \
    k0 = l0 ? _n : k0;                             \
} while (0)

// Markstein-refined division (bit-exact vs reference: absmax 0.0 in R3-R8)
__device__ __forceinline__ float fast_div(float a, float b) {
    float r = __builtin_amdgcn_rcpf(b);
    r = fmaf(fmaf(-b, r, 1.0f), r, r);
    float q = a * r;
    q = fmaf(fmaf(-b, q, a), r, q);
    return q;
}

// full cost given precomputed cost_bbox (cb)
__device__ __forceinline__ u64 eval_rest(const float4 pb, const float cb,
                                         const float4 gb, const float g_area,
                                         const int p) {
    const float area_p = (pb.z - pb.x) * (pb.w - pb.y);
    const float ltx = fmaxf(pb.x, gb.x), lty = fmaxf(pb.y, gb.y);
    const float rbx = fminf(pb.z, gb.z), rby = fminf(pb.w, gb.w);
    const float iw = fmaxf(rbx - ltx, 0.0f), ih = fmaxf(rby - lty, 0.0f);
    const float inter = iw * ih;
    const float uni = area_p + g_area - inter;
    const float iou = fast_div(inter, uni);
    const float ex1 = fminf(pb.x, gb.x), ey1 = fminf(pb.y, gb.y);
    const float ex2 = fmaxf(pb.z, gb.z), ey2 = fmaxf(pb.w, gb.w);
    const float area_e = (ex2 - ex1) * (ey2 - ey1);
    const float giou = iou - fast_div(area_e - uni, area_e);
    const float cost = cb + (1.0f - giou);
    return ((u64)__float_as_uint(cost) << 32) | (unsigned)p;
}

__global__ __launch_bounds__(256) void matcher_topk_kernel(
    const float* __restrict__ pred_box,  // [B, NP, 4]
    const float* __restrict__ gt_box,    // [B, NG, 4]
    int* __restrict__ out_pred,          // [B, NG*TOPK]
    int* __restrict__ out_gt,            // [B, NG*TOPK]
    int B, int NP, int NG)
{
    // XCD-pinned decomposition: batch = blockIdx % B. On MI355X B==8==#XCDs and
    // HW round-robins blocks over XCDs, so each XCD's L2 serves ONE batch's
    // pred slab (80 KB) for all its 150 pair-blocks.
    const int b = blockIdx.x % B;
    const int j = blockIdx.x / B;             // gt-pair index within batch

    const int t    = threadIdx.x;
    const int wid  = t >> 6;
    const int lane = t & 63;

    const float4* pbase = (const float4*)pred_box + (size_t)b * NP;
    const int NPm1  = NP - 1;
    const int NITER = (NP + 511) >> 9;        // 2 candidates per thread per iter

    __shared__ u64 smerge[WAVES][TOPK];

#define PROC1(pb_, idx_) do {                                            \
    const float _cb = fabsf(pb_.x - gb.x) + fabsf(pb_.y - gb.y)          \
                    + fabsf(pb_.z - gb.z) + fabsf(pb_.w - gb.w);         \
    const bool _valid = (idx_) < NP;                                     \
    const bool _want = (__float_as_uint(_cb) < thr_u) && _valid;         \
    if (__any((int)_want)) {                                             \
        u64 _k = eval_rest(pb_, _cb, gb, g_area, (idx_));                \
        _k = _valid ? _k : ~0ULL;                                        \
        INSERT(_k, k0, k1, k2, k3, k4);                                  \
        thr_u = (unsigned)(k4 >> 32);                                    \
    }                                                                    \
} while (0)

    // two gts processed SEQUENTIALLY: second scan hits warm L1/L2
    for (int half = 0; half < 2; ++half) {
        const int m = 2 * j + half;
        if (m >= NG) break;

        const float4 gb = ((const float4*)gt_box)[b * NG + m];
        const float g_area = (gb.z - gb.x) * (gb.w - gb.y);

        u64 k0 = ~0ULL, k1 = ~0ULL, k2 = ~0ULL, k3 = ~0ULL, k4 = ~0ULL;
        unsigned thr_u = 0xFFFFFFFFu;

        int p = t;
        for (int it = 0; it < NITER; ++it) {
            const int i0 = p, i1 = p + 256;
            const float4 pA = pbase[min(i0, NPm1)];
            const float4 pB = pbase[min(i1, NPm1)];
            PROC1(pA, i0);
            PROC1(pB, i1);
            p += 512;
        }

        // wave butterfly: merge sorted 5-lists across all 64 lanes
        #pragma unroll
        for (int off = 1; off < 64; off <<= 1) {
            const u64 b0 = __shfl_xor(k0, off);
            const u64 b1 = __shfl_xor(k1, off);
            const u64 b2 = __shfl_xor(k2, off);
            const u64 b3 = __shfl_xor(k3, off);
            const u64 b4 = __shfl_xor(k4, off);
            u64 m0 = k0 < b4 ? k0 : b4;
            u64 m1 = k1 < b3 ? k1 : b3;
            u64 m2 = k2 < b2 ? k2 : b2;
            u64 m3 = k3 < b1 ? k3 : b1;
            u64 m4 = k4 < b0 ? k4 : b0;
            CE(m0, m1); CE(m3, m4); CE(m2, m4); CE(m2, m3); CE(m1, m4);
            CE(m0, m3); CE(m0, m2); CE(m1, m3); CE(m1, m2);
            k0 = m0; k1 = m1; k2 = m2; k3 = m3; k4 = m4;
        }

        // cross-wave merge via LDS (4 sorted 5-lists -> final 5)
        if (lane == 0) {
            smerge[wid][0] = k0; smerge[wid][1] = k1; smerge[wid][2] = k2;
            smerge[wid][3] = k3; smerge[wid][4] = k4;
        }
        __syncthreads();

        if (t == 0) {
            int head[WAVES];
            #pragma unroll
            for (int w = 0; w < WAVES; ++w) head[w] = 0;
            const int baseo = (b * NG + m) * TOPK;
            #pragma unroll
            for (int r = 0; r < TOPK; ++r) {
                u64 best = ~0ULL; int bw = 0;
                #pragma unroll
                for (int w = 0; w < WAVES; ++w) {
                    const u64 v = smerge[w][head[w]];
                    if (v < best) { best = v; bw = w; }
                }
                head[bw]++;
                out_pred[baseo + r] = (int)(unsigned)(best & 0xFFFFFFFFu);
                out_gt[baseo + r]   = m;
            }
        }
        __syncthreads();   // smerge reused by next task
    }
#undef PROC1
}

extern "C" void kernel_launch(void* const* d_in, const int* in_sizes, int n_in,
                              void* d_out, int out_size, void* d_ws, size_t ws_size,
                              hipStream_t stream) {
    const float* pred_box = (const float*)d_in[0];   // [B, NP, 4]
    const float* gt_box   = (const float*)d_in[2];   // [B, NG, 4]

    const int NP = 5000;
    const int B  = in_sizes[1] / NP;                 // pred_obj is [B, NP]
    const int NG = in_sizes[3] / B;                  // gt_obj is [B, NG]

    int* out_pred = (int*)d_out;
    int* out_gt   = out_pred + B * NG * TOPK;

    const int pairsPerB = (NG + 1) >> 1;
    const int blocks = B * pairsPerB;                // 1200: XCD-bijective (8×150)
    hipLaunchKernelGGL(matcher_topk_kernel, dim3(blocks), dim3(256), 0, stream,
                       pred_box, gt_box, out_pred, out_gt, B, NP, NG);
}

// Round 10
// 39.047 us; speedup vs baseline: 1.1603x; 1.1603x over previous
//
#include <hip/hip_runtime.h>

#pragma clang fp contract(off)

typedef unsigned long long u64;

#define TOPK 5
#define WAVES 4   // 4 waves/block: waves {0,1} -> gt0, waves {2,3} -> gt1

// branchless compare-exchange on u64 keys (ascending)
#define CE(x, y) do { const u64 _a = (x), _b = (y); const bool _l = _b < _a; \
                      (x) = _l ? _b : _a; (y) = _l ? _a : _b; } while (0)

// branchless sorted-insert of nk into ascending 5-list
#define INSERT(nk, k0, k1, k2, k3, k4) do {        \
    const u64 _n = (nk);                           \
    const bool l0 = _n < k0;                       \
    const bool l1 = _n < k1;                       \
    const bool l2 = _n < k2;                       \
    const bool l3 = _n < k3;                       \
    const bool l4 = _n < k4;                       \
    k4 = l4 ? (l3 ? k3 : _n) : k4;                 \
    k3 = l3 ? (l2 ? k2 : _n) : k3;                 \
    k2 = l2 ? (l1 ? k1 : _n) : k2;                 \
    k1 = l1 ? (l0 ? k0 : _n) : k1;                 \
    k0 = l0 ? _n : k0;                             \
} while (0)

// Markstein-refined division (bit-exact vs reference: absmax 0.0 in R3-R9)
__device__ __forceinline__ float fast_div(float a, float b) {
    float r = __builtin_amdgcn_rcpf(b);
    r = fmaf(fmaf(-b, r, 1.0f), r, r);
    float q = a * r;
    q = fmaf(fmaf(-b, q, a), r, q);
    return q;
}

// full cost given precomputed cost_bbox (cb)
__device__ __forceinline__ u64 eval_rest(const float4 pb, const float cb,
                                         const float4 gb, const float g_area,
                                         const int p) {
    const float area_p = (pb.z - pb.x) * (pb.w - pb.y);
    const float ltx = fmaxf(pb.x, gb.x), lty = fmaxf(pb.y, gb.y);
    const float rbx = fminf(pb.z, gb.z), rby = fminf(pb.w, gb.w);
    const float iw = fmaxf(rbx - ltx, 0.0f), ih = fmaxf(rby - lty, 0.0f);
    const float inter = iw * ih;
    const float uni = area_p + g_area - inter;
    const float iou = fast_div(inter, uni);
    const float ex1 = fminf(pb.x, gb.x), ey1 = fminf(pb.y, gb.y);
    const float ex2 = fmaxf(pb.z, gb.z), ey2 = fmaxf(pb.w, gb.w);
    const float area_e = (ex2 - ex1) * (ey2 - ey1);
    const float giou = iou - fast_div(area_e - uni, area_e);
    const float cost = cb + (1.0f - giou);
    return ((u64)__float_as_uint(cost) << 32) | (unsigned)p;
}

__global__ __launch_bounds__(64 * WAVES) void matcher_topk_kernel(
    const float* __restrict__ pred_box,  // [B, NP, 4]
    const float* __restrict__ gt_box,    // [B, NG, 4]
    int* __restrict__ out_pred,          // [B, NG*TOPK]
    int* __restrict__ out_gt,            // [B, NG*TOPK]
    int B, int NP, int NG)
{
    const int pairsPerB = (NG + 1) >> 1;
    const int tp = blockIdx.x;               // one block per (b, gt-pair)
    const int b  = tp / pairsPerB;
    const int j  = tp - b * pairsPerB;
    const int m0 = 2 * j;
    const bool has1 = (m0 + 1 < NG);

    const int wid  = threadIdx.x >> 6;
    const int lane = threadIdx.x & 63;
    const int myGt = wid >> 1;               // 0 or 1
    const int half = wid & 1;                // pred half

    const float4 gb = ((const float4*)gt_box)[b * NG + (myGt ? (has1 ? m0 + 1 : m0) : m0)];
    const float g_area = (gb.z - gb.x) * (gb.w - gb.y);

    const int NPm1 = NP - 1;
    const int hN   = (NP + 1) >> 1;
    const int start = half ? hN : 0;
    const int pend  = half ? NP : hN;
    int niter = (pend - start + 255) >> 8;   // 256 preds per iteration
    niter += (niter & 1);                    // even (pair-processed loop)

    u64 k0 = ~0ULL, k1 = ~0ULL, k2 = ~0ULL, k3 = ~0ULL, k4 = ~0ULL;
    unsigned thr_u = 0xFFFFFFFFu;            // u32 view of k4's cost (cost>=0)

    const float4* pbase = (const float4*)pred_box + (size_t)b * NP;

#define LOADG(it, ra, rb, rc, rd) do {                        \
    const int _i = start + (it) * 256 + lane;                 \
    ra = pbase[min(_i,       NPm1)];                          \
    rb = pbase[min(_i + 64,  NPm1)];                          \
    rc = pbase[min(_i + 128, NPm1)];                          \
    rd = pbase[min(_i + 192, NPm1)];                          \
} while (0)

#define PROC1(pb_, idx_) do {                                            \
    const float _cb = fabsf(pb_.x - gb.x) + fabsf(pb_.y - gb.y)          \
                    + fabsf(pb_.z - gb.z) + fabsf(pb_.w - gb.w);         \
    const bool _valid = (idx_) < pend;                                   \
    const bool _want = (__float_as_uint(_cb) < thr_u) && _valid;         \
    if (__any((int)_want)) {                                             \
        u64 _k = eval_rest(pb_, _cb, gb, g_area, (idx_));                \
        _k = _valid ? _k : ~0ULL;                                        \
        INSERT(_k, k0, k1, k2, k3, k4);                                  \
        thr_u = (unsigned)(k4 >> 32);                                    \
    }                                                                    \
} while (0)

#define PROCG(it, ra, rb, rc, rd) do {                        \
    const int _i0 = start + (it) * 256 + lane;                \
    PROC1(ra, _i0);                                           \
    PROC1(rb, _i0 + 64);                                      \
    PROC1(rc, _i0 + 128);                                     \
    PROC1(rd, _i0 + 192);                                     \
} while (0)

    float4 eA, eB, eC, eD;   // even-iteration buffer
    float4 oA, oB, oC, oD;   // odd-iteration buffer
    LOADG(0, eA, eB, eC, eD);
    LOADG(1, oA, oB, oC, oD);

    const int nOuter = niter >> 1;
    for (int k = 0; k < nOuter; ++k) {
        const int itE = 2 * k;
        PROCG(itE, eA, eB, eC, eD);
        // prefetch next even chunk UNCONDITIONALLY (clamped addresses; no
        // branch => straight-line body the scheduler can pipeline)
        LOADG(itE + 2, eA, eB, eC, eD);
        // pin: forbid the scheduler from sinking the loads below the
        // following compute (R6/R7 showed it sinks them otherwise)
        __builtin_amdgcn_sched_barrier(0);
        PROCG(itE + 1, oA, oB, oC, oD);
        LOADG(itE + 3, oA, oB, oC, oD);
        __builtin_amdgcn_sched_barrier(0);
    }

#undef LOADG
#undef PROC1
#undef PROCG

    // wave butterfly: merge sorted 5-lists across all 64 lanes
    #pragma unroll
    for (int off = 1; off < 64; off <<= 1) {
        const u64 b0 = __shfl_xor(k0, off);
        const u64 b1 = __shfl_xor(k1, off);
        const u64 b2 = __shfl_xor(k2, off);
        const u64 b3 = __shfl_xor(k3, off);
        const u64 b4 = __shfl_xor(k4, off);
        u64 m0_ = k0 < b4 ? k0 : b4;
        u64 m1_ = k1 < b3 ? k1 : b3;
        u64 m2_ = k2 < b2 ? k2 : b2;
        u64 m3_ = k3 < b1 ? k3 : b1;
        u64 m4_ = k4 < b0 ? k4 : b0;
        CE(m0_, m1_); CE(m3_, m4_); CE(m2_, m4_); CE(m2_, m3_); CE(m1_, m4_);
        CE(m0_, m3_); CE(m0_, m2_); CE(m1_, m3_); CE(m1_, m2_);
        k0 = m0_; k1 = m1_; k2 = m2_; k3 = m3_; k4 = m4_;
    }

    // cross-wave merge via LDS: per gt, 2 sorted 5-lists -> final 5
    __shared__ u64 lds[WAVES][TOPK];
    if (lane == 0) {
        lds[wid][0] = k0; lds[wid][1] = k1; lds[wid][2] = k2;
        lds[wid][3] = k3; lds[wid][4] = k4;
    }
    __syncthreads();

    if (threadIdx.x < 2) {
        const int which = threadIdx.x;       // gt0 / gt1
        if (which == 0 || has1) {
            const int mm = m0 + which;
            int h0 = 0, h1 = 0;
            const int base = (b * NG + mm) * TOPK;
            #pragma unroll
            for (int r = 0; r < TOPK; ++r) {
                const u64 v0 = lds[which * 2][h0];
                const u64 v1 = lds[which * 2 + 1][h1];
                const bool t = v0 < v1;
                const u64 best = t ? v0 : v1;
                h0 += t; h1 += !t;
                out_pred[base + r] = (int)(unsigned)(best & 0xFFFFFFFFu);
                out_gt[base + r]   = mm;
            }
        }
    }
}

extern "C" void kernel_launch(void* const* d_in, const int* in_sizes, int n_in,
                              void* d_out, int out_size, void* d_ws, size_t ws_size,
                              hipStream_t stream) {
    const float* pred_box = (const float*)d_in[0];   // [B, NP, 4]
    const float* gt_box   = (const float*)d_in[2];   // [B, NG, 4]

    const int NP = 5000;
    const int B  = in_sizes[1] / NP;                 // pred_obj is [B, NP]
    const int NG = in_sizes[3] / B;                  // gt_obj is [B, NG]

    int* out_pred = (int*)d_out;
    int* out_gt   = out_pred + B * NG * TOPK;

    const int pairsPerB = (NG + 1) >> 1;
    const int blocks = B * pairsPerB;                // one block per gt-pair
    hipLaunchKernelGGL(matcher_topk_kernel, dim3(blocks), dim3(64 * WAVES), 0, stream,
                       pred_box, gt_box, out_pred, out_gt, B, NP, NG);
}

// Round 12
// 37.255 us; speedup vs baseline: 1.2161x; 1.0481x over previous
//
#include <hip/hip_runtime.h>

#pragma clang fp contract(off)

typedef unsigned long long u64;
typedef float f4 __attribute__((ext_vector_type(4)));   // plain ext_vector: asm-friendly

#define TOPK 5
#define WAVES 4   // waves {0,1} -> gt0, waves {2,3} -> gt1

// branchless compare-exchange on u64 keys (ascending)
#define CE(x, y) do { const u64 _a = (x), _b = (y); const bool _l = _b < _a; \
                      (x) = _l ? _b : _a; (y) = _l ? _a : _b; } while (0)

// Markstein-refined division (bit-exact vs reference: absmax 0.0 in R3-R10)
__device__ __forceinline__ float fast_div(float a, float b) {
    float r = __builtin_amdgcn_rcpf(b);
    r = fmaf(fmaf(-b, r, 1.0f), r, r);
    float q = a * r;
    q = fmaf(fmaf(-b, q, a), r, q);
    return q;
}

__device__ __forceinline__ u64 eval_key(const f4 pb, const f4 gb,
                                        const float g_area, const int p) {
    const float area_p = (pb.z - pb.x) * (pb.w - pb.y);
    const float cost_bbox = fabsf(pb.x - gb.x) + fabsf(pb.y - gb.y)
                          + fabsf(pb.z - gb.z) + fabsf(pb.w - gb.w);
    const float ltx = fmaxf(pb.x, gb.x), lty = fmaxf(pb.y, gb.y);
    const float rbx = fminf(pb.z, gb.z), rby = fminf(pb.w, gb.w);
    const float iw = fmaxf(rbx - ltx, 0.0f), ih = fmaxf(rby - lty, 0.0f);
    const float inter = iw * ih;
    const float uni = area_p + g_area - inter;
    const float iou = fast_div(inter, uni);
    const float ex1 = fminf(pb.x, gb.x), ey1 = fminf(pb.y, gb.y);
    const float ex2 = fmaxf(pb.z, gb.z), ey2 = fmaxf(pb.w, gb.w);
    const float area_e = (ex2 - ex1) * (ey2 - ey1);
    const float giou = iou - fast_div(area_e - uni, area_e);
    const float cost = cost_bbox + (1.0f - giou);
    return ((u64)__float_as_uint(cost) << 32) | (unsigned)p;
}

__global__ __launch_bounds__(64 * WAVES) void matcher_topk_kernel(
    const float* __restrict__ pred_box,  // [B, NP, 4]
    const float* __restrict__ gt_box,    // [B, NG, 4]
    int* __restrict__ out_pred,          // [B, NG*TOPK]
    int* __restrict__ out_gt,            // [B, NG*TOPK]
    int B, int NP, int NG)
{
    const int pairsPerB = (NG + 1) >> 1;
    const int tp = blockIdx.x;               // one block per (b, gt-pair)
    const int b  = tp / pairsPerB;
    const int j  = tp - b * pairsPerB;
    const int m0 = 2 * j;
    const bool has1 = (m0 + 1 < NG);

    const int wid  = threadIdx.x >> 6;
    const int lane = threadIdx.x & 63;
    const int myGt = wid >> 1;               // 0 or 1
    const int half = wid & 1;                // pred half

    const f4 gb = ((const f4*)gt_box)[b * NG + (myGt ? (has1 ? m0 + 1 : m0) : m0)];
    const float g_area = (gb.z - gb.x) * (gb.w - gb.y);

    const int NPm1  = NP - 1;
    const int hN    = (NP + 1) >> 1;
    const int start = half ? hN : 0;
    const int pend  = half ? NP : hN;
    // groups of 256 preds (4 loads/lane); even count for the 2-phase pipeline
    int ngroups = (pend - start + 255) >> 8;
    ngroups += (ngroups & 1);

    u64 k0 = ~0ULL, k1 = ~0ULL, k2 = ~0ULL, k3 = ~0ULL, k4 = ~0ULL;

    const f4* pbase = (const f4*)pred_box + (size_t)b * NP;

// inline-asm loads: compiler cannot sink/rematerialize these
#define GLOAD(g, rA, rB, rC, rD) do {                                        \
    const int _i = start + (g) * 256 + lane;                                 \
    const f4* _p0 = pbase + min(_i,       NPm1);                             \
    const f4* _p1 = pbase + min(_i + 64,  NPm1);                             \
    const f4* _p2 = pbase + min(_i + 128, NPm1);                             \
    const f4* _p3 = pbase + min(_i + 192, NPm1);                             \
    asm volatile("global_load_dwordx4 %0, %1, off" : "=v"(rA) : "v"(_p0));   \
    asm volatile("global_load_dwordx4 %0, %1, off" : "=v"(rB) : "v"(_p1));   \
    asm volatile("global_load_dwordx4 %0, %1, off" : "=v"(rC) : "v"(_p2));   \
    asm volatile("global_load_dwordx4 %0, %1, off" : "=v"(rD) : "v"(_p3));   \
} while (0)

// retire the oldest in-flight group (steady state: 8 outstanding -> 4).
// sched_barrier right after: rule #18 (compiler hoists reg-only ops past
// inline-asm waitcnt otherwise).
#define GWAIT() do {                                   \
    asm volatile("s_waitcnt vmcnt(4)");                \
    __builtin_amdgcn_sched_barrier(0);                 \
} while (0)

// straight-line: 4 evals (ILP), mask invalid, sort4, bitonic-merge into top5
#define PROCG(g, rA, rB, rC, rD) do {                                        \
    const int _i0 = start + (g) * 256 + lane;                                \
    u64 kA = eval_key(rA, gb, g_area, _i0);                                  \
    u64 kB = eval_key(rB, gb, g_area, _i0 + 64);                             \
    u64 kC = eval_key(rC, gb, g_area, _i0 + 128);                            \
    u64 kD = eval_key(rD, gb, g_area, _i0 + 192);                            \
    kA = (_i0       < pend) ? kA : ~0ULL;                                    \
    kB = (_i0 + 64  < pend) ? kB : ~0ULL;                                    \
    kC = (_i0 + 128 < pend) ? kC : ~0ULL;                                    \
    kD = (_i0 + 192 < pend) ? kD : ~0ULL;                                    \
    CE(kA, kB); CE(kC, kD); CE(kA, kC); CE(kB, kD); CE(kB, kC);              \
    u64 n0 = k0;                                                             \
    u64 n1 = k1 < kD ? k1 : kD;                                              \
    u64 n2 = k2 < kC ? k2 : kC;                                              \
    u64 n3 = k3 < kB ? k3 : kB;                                              \
    u64 n4 = k4 < kA ? k4 : kA;                                              \
    CE(n0, n1); CE(n3, n4); CE(n2, n4); CE(n2, n3); CE(n1, n4);              \
    CE(n0, n3); CE(n0, n2); CE(n1, n3); CE(n1, n2);                          \
    k0 = n0; k1 = n1; k2 = n2; k3 = n3; k4 = n4;                             \
} while (0)

    f4 eA, eB, eC, eD;   // even-phase buffer
    f4 oA, oB, oC, oD;   // odd-phase buffer

    GLOAD(0, eA, eB, eC, eD);
    GLOAD(1, oA, oB, oC, oD);

    for (int g = 0; g < ngroups; g += 2) {
        GWAIT();                                // group g landed
        PROCG(g, eA, eB, eC, eD);
        __builtin_amdgcn_sched_barrier(0);      // reads of eA.. done before refill
        GLOAD(g + 2, eA, eB, eC, eD);           // clamped; harmless over-issue at tail
        GWAIT();                                // group g+1 landed
        PROCG(g + 1, oA, oB, oC, oD);
        __builtin_amdgcn_sched_barrier(0);
        GLOAD(g + 3, oA, oB, oC, oD);
    }

    // ---- R11 bug fix: the last two GLOADs are still in flight here. Drain
    // them, and keep their destination registers LIVE past the drain so the
    // allocator cannot recycle them while hardware still owns them (the
    // clobber-on-return was R11's absmax=1.1e9).
    asm volatile("s_waitcnt vmcnt(0)");
    __builtin_amdgcn_sched_barrier(0);
    asm volatile("" :: "v"(eA), "v"(eB), "v"(eC), "v"(eD),
                       "v"(oA), "v"(oB), "v"(oC), "v"(oD));

#undef GLOAD
#undef GWAIT
#undef PROCG

    // wave butterfly: merge sorted 5-lists across all 64 lanes
    #pragma unroll
    for (int off = 1; off < 64; off <<= 1) {
        const u64 b0 = __shfl_xor(k0, off);
        const u64 b1 = __shfl_xor(k1, off);
        const u64 b2 = __shfl_xor(k2, off);
        const u64 b3 = __shfl_xor(k3, off);
        const u64 b4 = __shfl_xor(k4, off);
        u64 m0_ = k0 < b4 ? k0 : b4;
        u64 m1_ = k1 < b3 ? k1 : b3;
        u64 m2_ = k2 < b2 ? k2 : b2;
        u64 m3_ = k3 < b1 ? k3 : b1;
        u64 m4_ = k4 < b0 ? k4 : b0;
        CE(m0_, m1_); CE(m3_, m4_); CE(m2_, m4_); CE(m2_, m3_); CE(m1_, m4_);
        CE(m0_, m3_); CE(m0_, m2_); CE(m1_, m3_); CE(m1_, m2_);
        k0 = m0_; k1 = m1_; k2 = m2_; k3 = m3_; k4 = m4_;
    }

    // cross-wave merge via LDS: per gt, 2 sorted 5-lists -> final 5
    __shared__ u64 lds[WAVES][TOPK];
    if (lane == 0) {
        lds[wid][0] = k0; lds[wid][1] = k1; lds[wid][2] = k2;
        lds[wid][3] = k3; lds[wid][4] = k4;
    }
    __syncthreads();

    if (threadIdx.x < 2) {
        const int which = threadIdx.x;       // gt0 / gt1
        if (which == 0 || has1) {
            const int mm = m0 + which;
            int h0 = 0, h1 = 0;
            const int base = (b * NG + mm) * TOPK;
            #pragma unroll
            for (int r = 0; r < TOPK; ++r) {
                const u64 v0 = lds[which * 2][h0];
                const u64 v1 = lds[which * 2 + 1][h1];
                const bool t = v0 < v1;
                const u64 best = t ? v0 : v1;
                h0 += t; h1 += !t;
                out_pred[base + r] = (int)(unsigned)(best & 0xFFFFFFFFu);
                out_gt[base + r]   = mm;
            }
        }
    }
}

extern "C" void kernel_launch(void* const* d_in, const int* in_sizes, int n_in,
                              void* d_out, int out_size, void* d_ws, size_t ws_size,
                              hipStream_t stream) {
    const float* pred_box = (const float*)d_in[0];   // [B, NP, 4]
    const float* gt_box   = (const float*)d_in[2];   // [B, NG, 4]

    const int NP = 5000;
    const int B  = in_sizes[1] / NP;                 // pred_obj is [B, NP]
    const int NG = in_sizes[3] / B;                  // gt_obj is [B, NG]

    int* out_pred = (int*)d_out;
    int* out_gt   = out_pred + B * NG * TOPK;

    const int pairsPerB = (NG + 1) >> 1;
    const int blocks = B * pairsPerB;                // one block per gt-pair
    hipLaunchKernelGGL(matcher_topk_kernel, dim3(blocks), dim3(64 * WAVES), 0, stream,
                       pred_box, gt_box, out_pred, out_gt, B, NP, NG);
}